// Round 14
// baseline (1379.822 us; speedup 1.0000x reference)
//
#include <hip/hip_runtime.h>

#define N0c 100000
#define N1c 20000
#define Ec 320000
#define NBLK ((Ec + 1023) / 1024)   // 313 blocks for length bucketing

typedef _Float16 f16;
typedef _Float16 f16x2 __attribute__((ext_vector_type(2)));

#define LOG2E 1.442695040888963f

__device__ __forceinline__ float sigm(float x) {
    return __builtin_amdgcn_rcpf(1.f + __builtin_amdgcn_exp2f(-LOG2E * x));
}
__device__ __forceinline__ float tanh_(float x) {
    return 2.f * __builtin_amdgcn_rcpf(1.f + __builtin_amdgcn_exp2f(-2.f * LOG2E * x)) - 1.f;
}
__device__ __forceinline__ float dot2(uint w, uint v, float acc) {
#if __has_builtin(__builtin_amdgcn_fdot2)
    return __builtin_amdgcn_fdot2(__builtin_bit_cast(f16x2, w),
                                  __builtin_bit_cast(f16x2, v), acc, false);
#else
    f16x2 a = __builtin_bit_cast(f16x2, w);
    f16x2 b = __builtin_bit_cast(f16x2, v);
    return acc + (float)a[0] * (float)b[0] + (float)a[1] * (float)b[1];
#endif
}
__device__ __forceinline__ uint packh(float a, float b) {
    f16x2 p;
    p[0] = (f16)a;
    p[1] = (f16)b;
    return __builtin_bit_cast(uint, p);
}

// ---------------- length bucketing (deterministic counting sort, from R2) ---
__global__ void count_kernel(const int* __restrict__ elen, int* __restrict__ bc) {
    __shared__ int h[8];
    if (threadIdx.x < 8) h[threadIdx.x] = 0;
    __syncthreads();
    const int base = blockIdx.x * 1024;
    for (int i = threadIdx.x; i < 1024; i += 256) {
        int e = base + i;
        if (e < Ec) atomicAdd(&h[elen[e] - 1], 1);
    }
    __syncthreads();
    if (threadIdx.x < 8) bc[blockIdx.x * 8 + threadIdx.x] = h[threadIdx.x];
}

__global__ void offs_kernel(const int* __restrict__ bc, int* __restrict__ bo) {
    __shared__ int s[NBLK * 8];
    __shared__ int base[8];
    const int tid = threadIdx.x;
    for (int i = tid; i < NBLK * 8; i += 256) s[i] = bc[i];
    __syncthreads();
    if (tid == 0) {
        int tot[8];
        for (int b = 0; b < 8; ++b) {
            int t = 0;
            for (int blk = 0; blk < NBLK; ++blk) t += s[blk * 8 + b];
            tot[b] = t;
        }
        int run = 0;
        for (int b = 0; b < 8; ++b) { base[b] = run; run += tot[b]; }
    }
    __syncthreads();
    if (tid < 8) {
        int run = base[tid];
        for (int blk = 0; blk < NBLK; ++blk) {
            int t = s[blk * 8 + tid];
            s[blk * 8 + tid] = run;
            run += t;
        }
    }
    __syncthreads();
    for (int i = tid; i < NBLK * 8; i += 256) bo[i] = s[i];
}

__global__ void scatter2_kernel(const int* __restrict__ elen, const int* __restrict__ bo,
                                int* __restrict__ lperm, int* __restrict__ lenq) {
    __shared__ int cnt[256][9];
    const int tid = threadIdx.x;
    const int base = blockIdx.x * 1024 + tid * 4;
    int lens[4];
    int lc0 = 0, lc1 = 0, lc2 = 0, lc3 = 0, lc4 = 0, lc5 = 0, lc6 = 0, lc7 = 0;
    #pragma unroll
    for (int j = 0; j < 4; ++j) {
        int e = base + j;
        int l = (e < Ec) ? elen[e] - 1 : -1;
        lens[j] = l;
        lc0 += (l == 0); lc1 += (l == 1); lc2 += (l == 2); lc3 += (l == 3);
        lc4 += (l == 4); lc5 += (l == 5); lc6 += (l == 6); lc7 += (l == 7);
    }
    cnt[tid][0] = lc0; cnt[tid][1] = lc1; cnt[tid][2] = lc2; cnt[tid][3] = lc3;
    cnt[tid][4] = lc4; cnt[tid][5] = lc5; cnt[tid][6] = lc6; cnt[tid][7] = lc7;
    __syncthreads();
    if (tid < 8) {
        int run = bo[blockIdx.x * 8 + tid];
        for (int i = 0; i < 256; ++i) {
            int t = cnt[i][tid];
            cnt[i][tid] = run;
            run += t;
        }
    }
    __syncthreads();
    #pragma unroll
    for (int b = 0; b < 8; ++b) {
        int p = cnt[tid][b];
        #pragma unroll
        for (int j = 0; j < 4; ++j) {
            if (lens[j] == b) { lperm[p] = base + j; lenq[p] = b + 1; ++p; }
        }
    }
}

// ---------------- dst bucketing (for node segment-sum) ---------------------
__global__ void dhist_kernel(const int* __restrict__ dst, int* __restrict__ hist) {
    int e = blockIdx.x * blockDim.x + threadIdx.x;
    if (e < Ec) atomicAdd(&hist[dst[e]], 1);
}

__global__ void dscan_kernel(int* __restrict__ hist) {
    __shared__ int s[N1c];
    __shared__ int psum[256];
    const int tid = threadIdx.x;
    const int CH = (N1c + 255) / 256;
    for (int i = tid; i < N1c; i += 256) s[i] = hist[i];
    __syncthreads();
    int loc = 0;
    #pragma unroll 1
    for (int j = 0; j < CH; ++j) {
        int i = tid * CH + j;
        if (i < N1c) loc += s[i];
    }
    psum[tid] = loc;
    __syncthreads();
    if (tid == 0) {
        int run = 0;
        for (int t = 0; t < 256; ++t) { int v = psum[t]; psum[t] = run; run += v; }
    }
    __syncthreads();
    int run = psum[tid];
    #pragma unroll 1
    for (int j = 0; j < CH; ++j) {
        int i = tid * CH + j;
        if (i < N1c) { int v = s[i]; s[i] = run; run += v; }
    }
    __syncthreads();
    for (int i = tid; i < N1c; i += 256) hist[i] = s[i];
}

__global__ void dscatter_kernel(const int* __restrict__ dst, int* __restrict__ cursor,
                                int* __restrict__ perm) {
    int e = blockIdx.x * blockDim.x + threadIdx.x;
    if (e < Ec) {
        int pos = atomicAdd(&cursor[dst[e]], 1);
        perm[pos] = e;
    }
}

// ---------------- MLP weight prep (eW^T packed pairs, per-lane) ------------
__global__ void wprep_kernel(const float* __restrict__ eW, uint* __restrict__ ewc) {
    int idx = blockIdx.x * 256 + threadIdx.x;
    if (idx < 24 * 256) {
        int c4 = idx >> 8, l = (idx >> 2) & 63, i = idx & 3;
        int cp = c4 * 4 + i;
        ewc[idx] = packh(eW[(2 * cp) * 64 + l], eW[(2 * cp + 1) * 64 + l]);
    }
}

// ---------------- X pre-pack: Xpk[e][t][8] uint (f16 pairs), orig order ----
__global__ void xprep_kernel(const float* __restrict__ ef, const float* __restrict__ st,
                             uint* __restrict__ Xpk) {
    int idx = blockIdx.x * 256 + threadIdx.x;   // e*8 + t
    int e = idx >> 3, t = idx & 7;
    float v[16];
    #pragma unroll
    for (int f = 0; f < 15; ++f) v[f] = ef[(size_t)e * 120 + t * 15 + f];
    v[15] = st[(size_t)e * 8 + t];
    uint* dst = Xpk + (size_t)idx * 8;
    #pragma unroll
    for (int j = 0; j < 8; ++j) dst[j] = packh(v[2 * j], v[2 * j + 1]);
}

// ---------------- LSTM: lane=(edge, quarter), LDS-broadcast weights --------
// Wave = 16 edges x 4 unit-quarters. Per-lane regs: hall[32] (all units,
// packed f16 pairs), cf[16] f32 (own units), xv from Xpk. Weights in LDS:
// row(gm) at byte gm*176 + ((gm>>4)&3)*16  ->  for lane quarter q the shift
// is uniformly q*16 (g*64 contributes 0 mod 4), so rows are base+static.
// Quarter addr deltas = +4/+8/+12 banks -> conflict-free 4-addr broadcast.

__device__ __forceinline__ float gate_full(const char* row, const uint* hall,
                                           const uint* xv, float acc) {
    const uint4* W = (const uint4*)row;
    #pragma unroll
    for (int b = 0; b < 8; ++b) {
        uint4 w = W[b];
        acc = dot2(w.x, hall[b * 4 + 0], acc);
        acc = dot2(w.y, hall[b * 4 + 1], acc);
        acc = dot2(w.z, hall[b * 4 + 2], acc);
        acc = dot2(w.w, hall[b * 4 + 3], acc);
    }
    #pragma unroll
    for (int b = 0; b < 2; ++b) {
        uint4 w = W[8 + b];
        acc = dot2(w.x, xv[b * 4 + 0], acc);
        acc = dot2(w.y, xv[b * 4 + 1], acc);
        acc = dot2(w.z, xv[b * 4 + 2], acc);
        acc = dot2(w.w, xv[b * 4 + 3], acc);
    }
    return acc;
}
__device__ __forceinline__ float gate_x(const char* row, const uint* xv, float acc) {
    const uint4* W = (const uint4*)row;
    #pragma unroll
    for (int b = 0; b < 2; ++b) {
        uint4 w = W[8 + b];
        acc = dot2(w.x, xv[b * 4 + 0], acc);
        acc = dot2(w.y, xv[b * 4 + 1], acc);
        acc = dot2(w.z, xv[b * 4 + 2], acc);
        acc = dot2(w.w, xv[b * 4 + 3], acc);
    }
    return acc;
}

__global__ __launch_bounds__(512)
void lstm_q_kernel(const float* __restrict__ Whh, const float* __restrict__ Wih,
                   const float* __restrict__ lb, const uint* __restrict__ Xpk,
                   const int* __restrict__ lperm, const int* __restrict__ lenq,
                   f16* __restrict__ hb)
{
    __shared__ __align__(16) uint wL[11296];   // 45.2 KB staggered rows
    __shared__ float bL[256];                  // 1 KB

    const int tid = threadIdx.x;
    for (int idx = tid; idx < 256 * 40; idx += 512) {
        int gm = idx / 40, j2 = idx - gm * 40;
        float w0, w1;
        if (j2 < 32) {
            w0 = Whh[(2 * j2) * 256 + gm];
            w1 = Whh[(2 * j2 + 1) * 256 + gm];
        } else {
            int k = j2 - 32;
            w0 = Wih[(2 * k) * 256 + gm];
            w1 = Wih[(2 * k + 1) * 256 + gm];
        }
        // byte addr: gm*176 + ((gm>>4)&3)*16 + j2*4  -> uint index /4
        wL[gm * 44 + ((gm >> 4) & 3) * 4 + j2] = packh(w0, w1);
    }
    if (tid < 256) bL[tid] = lb[tid];
    __syncthreads();

    const int lane = tid & 63;
    const int wv = tid >> 6;
    const int q = lane >> 4;     // unit quarter: units q*16 .. q*16+16
    const int eo = lane & 15;    // edge within tile

    // lane-uniform LDS bases
    const char* wb = (const char*)wL + q * (16 * 176 + 16);  // + (g*64+ul)*176 + j2b*16
    const float* bq = bL + q * 16;                            // + g*64 + ul

    for (int tile = blockIdx.x * 8 + wv; tile < Ec / 16; tile += gridDim.x * 8) {
        const int i = tile * 16 + eo;
        const int oe = lperm[i];
        const int mylen = lenq[i];
        int tmax = mylen;
        tmax = max(tmax, __shfl_xor(tmax, 1));
        tmax = max(tmax, __shfl_xor(tmax, 2));
        tmax = max(tmax, __shfl_xor(tmax, 4));
        tmax = max(tmax, __shfl_xor(tmax, 8));

        const uint* xr = Xpk + (size_t)oe * 64;

        uint hall[32];
        float cf[16], hown[16];
        uint own8[8];
        uint xv[8];

        // ---- t = 0 (h == 0): x-part only ----
        {
            uint4 x0 = *(const uint4*)(xr);
            uint4 x1 = *(const uint4*)(xr + 4);
            xv[0] = x0.x; xv[1] = x0.y; xv[2] = x0.z; xv[3] = x0.w;
            xv[4] = x1.x; xv[5] = x1.y; xv[6] = x1.z; xv[7] = x1.w;
            #pragma unroll
            for (int ul = 0; ul < 16; ++ul) {
                float aI = gate_x(wb + (0 * 64 + ul) * 176, xv, bq[0 * 64 + ul]);
                float aF = gate_x(wb + (1 * 64 + ul) * 176, xv, bq[1 * 64 + ul]);
                float aG = gate_x(wb + (2 * 64 + ul) * 176, xv, bq[2 * 64 + ul]);
                float aO = gate_x(wb + (3 * 64 + ul) * 176, xv, bq[3 * 64 + ul]);
                float ig = sigm(aI), fg = sigm(aF), gg = tanh_(aG), og = sigm(aO);
                float cn = ig * gg;          // c0 = 0
                float hn = og * tanh_(cn);
                cf[ul] = cn;
                hown[ul] = hn;
                (void)fg;
            }
            #pragma unroll
            for (int k = 0; k < 8; ++k) own8[k] = packh(hown[2 * k], hown[2 * k + 1]);
            #pragma unroll
            for (int j2 = 0; j2 < 32; ++j2)
                hall[j2] = __shfl(own8[j2 & 7], (j2 >> 3) * 16 + eo);
        }

        // ---- t = 1 .. tmax-1 ----
        for (int t = 1; t < tmax; ++t) {
            uint4 x0 = *(const uint4*)(xr + t * 8);
            uint4 x1 = *(const uint4*)(xr + t * 8 + 4);
            xv[0] = x0.x; xv[1] = x0.y; xv[2] = x0.z; xv[3] = x0.w;
            xv[4] = x1.x; xv[5] = x1.y; xv[6] = x1.z; xv[7] = x1.w;
            const bool live = (t < mylen);
            #pragma unroll
            for (int ul = 0; ul < 16; ++ul) {
                float aI = gate_full(wb + (0 * 64 + ul) * 176, hall, xv, bq[0 * 64 + ul]);
                float aF = gate_full(wb + (1 * 64 + ul) * 176, hall, xv, bq[1 * 64 + ul]);
                float aG = gate_full(wb + (2 * 64 + ul) * 176, hall, xv, bq[2 * 64 + ul]);
                float aO = gate_full(wb + (3 * 64 + ul) * 176, hall, xv, bq[3 * 64 + ul]);
                float ig = sigm(aI), fg = sigm(aF), gg = tanh_(aG), og = sigm(aO);
                float cn = fg * cf[ul] + ig * gg;
                float hn = og * tanh_(cn);
                if (live) { cf[ul] = cn; hown[ul] = hn; }
            }
            #pragma unroll
            for (int k = 0; k < 8; ++k) own8[k] = packh(hown[2 * k], hown[2 * k + 1]);
            #pragma unroll
            for (int j2 = 0; j2 < 32; ++j2)
                hall[j2] = __shfl(own8[j2 & 7], (j2 >> 3) * 16 + eo);
        }

        // ---- write h (own quarter) to hb[orig_e][units] ----
        uint4* hp = (uint4*)(hb + (size_t)oe * 64 + q * 16);
        hp[0] = (uint4){own8[0], own8[1], own8[2], own8[3]};
        hp[1] = (uint4){own8[4], own8[5], own8[6], own8[7]};
    }
}

// ---------------- MLP: wave-per-edge, eW in registers, f16 dot2 ------------
__global__ __launch_bounds__(256, 2)
void mlp_kernel(const float* __restrict__ nf, const float* __restrict__ pw,
                const uint4* __restrict__ ewc4, const float* __restrict__ ebias,
                const int* __restrict__ src, const f16* __restrict__ hb,
                f16* __restrict__ mbuf)
{
    __shared__ __align__(16) f16 sCat[4][192];
    const int lane = threadIdx.x & 63;
    const int wv = threadIdx.x >> 6;

    uint ew[24][4];
    #pragma unroll
    for (int i = 0; i < 24; ++i) {
        uint4 v = ewc4[i * 64 + lane];
        ew[i][0] = v.x; ew[i][1] = v.y; ew[i][2] = v.z; ew[i][3] = v.w;
    }
    const float pwl = pw[lane], pwh = pw[64 + lane];
    const float ebl = ebias[lane];

    f16* myCat = sCat[wv];
    const int wid = blockIdx.x * 4 + wv;
    for (int e = wid; e < Ec; e += 2048) {
        const int s = src[e];
        float hs0 = nf[(size_t)s * 128 + lane];
        float hs1 = nf[(size_t)s * 128 + 64 + lane];
        float part = hs0 * pwl + hs1 * pwh;
        #pragma unroll
        for (int off = 32; off; off >>= 1) part += __shfl_xor(part, off);
        float he = (float)hb[(size_t)e * 64 + lane];
        myCat[lane] = (f16)(hs0 - part * pwl);
        myCat[64 + lane] = (f16)(hs1 - part * pwh);
        myCat[128 + lane] = (f16)he;
        const uint4* cp = (const uint4*)myCat;
        float m0 = 0.f, m1 = 0.f, m2 = 0.f, m3 = 0.f;
        #pragma unroll
        for (int i = 0; i < 24; ++i) {
            uint4 qv = cp[i];
            m0 = dot2(ew[i][0], qv.x, m0);
            m1 = dot2(ew[i][1], qv.y, m1);
            m2 = dot2(ew[i][2], qv.z, m2);
            m3 = dot2(ew[i][3], qv.w, m3);
        }
        float m = fmaxf(m0 + m1 + m2 + m3 + ebl, 0.f);
        mbuf[(size_t)e * 64 + lane] = (f16)m;
    }
}

// ---------------- Node kernel: segment-sum of m + node math ----------------
#define NB_WAVES 8
#define NB_THREADS (NB_WAVES * 64)
__global__ __launch_bounds__(NB_THREADS, 1)
void node_kernel(const float* __restrict__ nf,
                 const float* __restrict__ sgn,
                 const float* __restrict__ eW,
                 const float* __restrict__ ebias,
                 const float* __restrict__ nW,
                 const float* __restrict__ nbias,
                 const float* __restrict__ fcW,
                 const float* __restrict__ fcb,
                 const int* __restrict__ lnid,
                 const int* __restrict__ hist,
                 const int* __restrict__ perm,
                 const f16* __restrict__ m,
                 float* __restrict__ out,
                 int nWavesTotal)
{
    __shared__ float sEW[128 * 64];
    __shared__ float sNW[192 * 64];
    __shared__ float sFC[64 * 16];
    __shared__ float sCat[NB_WAVES][192];
    __shared__ float sAct[NB_WAVES][64];

    const int tid = threadIdx.x;
    for (int idx = tid; idx < 128 * 64; idx += NB_THREADS) sEW[idx] = eW[idx];
    for (int idx = tid; idx < 192 * 64; idx += NB_THREADS) sNW[idx] = nW[idx];
    for (int idx = tid; idx < 64 * 16; idx += NB_THREADS) sFC[idx] = fcW[idx];
    __syncthreads();

    const int lane = tid & 63;
    const int wv = tid >> 6;
    const int gwave = blockIdx.x * NB_WAVES + wv;

    const float ebv = ebias[lane];
    const float nbv = nbias[lane];
    const float fcbv = (lane < 16) ? fcb[lane] : 0.f;

    for (int n = gwave; n < N1c; n += nWavesTotal) {
        const int nid = lnid[n];
        float sh0 = nf[(size_t)nid * 128 + lane];
        float sh1 = nf[(size_t)nid * 128 + 64 + lane];
        sCat[wv][lane] = sh0;
        sCat[wv][64 + lane] = sh1;

        float tmp = ebv;
        #pragma unroll 8
        for (int cc = 0; cc < 128; ++cc) tmp += sCat[wv][cc] * sEW[cc * 64 + lane];

        const int o0 = (n == 0) ? 0 : hist[n - 1];
        const int o1 = hist[n];
        float av = 0.f;
        for (int base = o0; base < o1; base += 64) {
            int cnt = min(64, o1 - base);
            int pk = (lane < cnt) ? perm[base + lane] : 0;
            for (int j = 0; j < cnt; ++j) {
                int pe = __shfl(pk, j);
                av += (float)m[(size_t)pe * 64 + lane];
            }
        }

        float hu = (av - tmp) * sgn[n];
        sCat[wv][128 + lane] = hu;

        float acc = nbv;
        #pragma unroll 8
        for (int cc = 0; cc < 192; ++cc) acc += sCat[wv][cc] * sNW[cc * 64 + lane];
        acc = fmaxf(acc, 0.f);
        sAct[wv][lane] = acc;

        if (lane < 16) {
            float o = fcbv;
            #pragma unroll
            for (int j = 0; j < 64; ++j) o += sAct[wv][j] * sFC[j * 16 + lane];
            out[(size_t)n * 16 + lane] = o;
        }
    }
}

extern "C" void kernel_launch(void* const* d_in, const int* in_sizes, int n_in,
                              void* d_out, int out_size, void* d_ws, size_t ws_size,
                              hipStream_t stream) {
    const float* nf  = (const float*)d_in[0];
    const float* ef  = (const float*)d_in[1];
    const float* st  = (const float*)d_in[2];
    const float* sgn = (const float*)d_in[3];
    const float* pw  = (const float*)d_in[4];
    const float* Wih = (const float*)d_in[5];
    const float* Whh = (const float*)d_in[6];
    const float* lb  = (const float*)d_in[7];
    const float* eW  = (const float*)d_in[8];
    const float* eb  = (const float*)d_in[9];
    const float* nW  = (const float*)d_in[10];
    const float* nb  = (const float*)d_in[11];
    const float* fcW = (const float*)d_in[12];
    const float* fcb = (const float*)d_in[13];
    const int* elen = (const int*)d_in[14];
    const int* src  = (const int*)d_in[15];
    const int* dst  = (const int*)d_in[16];
    const int* lnid = (const int*)d_in[17];

    float* out = (float*)d_out;

    // ws layout (bytes)
    char* base = (char*)d_ws;
    int*  hist  = (int*) (base + 0);           // 80 KB
    int*  dperm = (int*) (base + 81920);       // 1.28 MB -> 1392640
    int*  bc    = (int*) (base + 1392640);     // 16 KB
    int*  bo    = (int*) (base + 1409024);     // 16 KB
    int*  lperm = (int*) (base + 1425408);     // 1.28 MB -> 2736128
    int*  lenq  = (int*) (base + 2736128);     // 1.28 MB -> 4046848
    uint* ewc   = (uint*)(base + 4046848);     // 24.5 KB -> 4079616
    uint* Xpk   = (uint*)(base + 4079616);     // 81.92 MB -> 85999616
    f16*  hb    = (f16*) (base + 85999616);    // 40.96 MB -> 126959616
    f16*  mbuf  = (f16*) (base + 126959616);   // 40.96 MB -> 167919616

    hipMemsetAsync(hist, 0, 81920, stream);

    // length sort (for LSTM tiles)
    count_kernel<<<NBLK, 256, 0, stream>>>(elen, bc);
    offs_kernel<<<1, 256, 0, stream>>>(bc, bo);
    scatter2_kernel<<<NBLK, 256, 0, stream>>>(elen, bo, lperm, lenq);

    // dst sort (for node segment-sum)
    dhist_kernel<<<1250, 256, 0, stream>>>(dst, hist);
    dscan_kernel<<<1, 256, 0, stream>>>(hist);
    dscatter_kernel<<<1250, 256, 0, stream>>>(dst, hist, dperm);

    wprep_kernel<<<24, 256, 0, stream>>>(eW, ewc);
    xprep_kernel<<<10000, 256, 0, stream>>>(ef, st, Xpk);

    lstm_q_kernel<<<1250, 512, 0, stream>>>(Whh, Wih, lb, Xpk, lperm, lenq, hb);

    mlp_kernel<<<512, 256, 0, stream>>>(nf, pw, (const uint4*)ewc, eb, src, hb, mbuf);

    node_kernel<<<512, NB_THREADS, 0, stream>>>(
        nf, sgn, eW, eb, nW, nb, fcW, fcb, lnid, hist, dperm, mbuf, out,
        512 * NB_WAVES);
}